// Round 6
// baseline (2831.626 us; speedup 1.0000x reference)
//
#include <hip/hip_runtime.h>
#include <hip/hip_bf16.h>
#include <stdint.h>

#define BATCH 1024
#define DIM   1024
#define HID   4096
#define TPTS  16

typedef __attribute__((ext_vector_type(8))) short  short8;
typedef __attribute__((ext_vector_type(4))) float  floatx4;

__device__ __forceinline__ unsigned short f32_to_bf16_bits(float f) {
    union { float f; unsigned u; } v; v.f = f;
    return (unsigned short)((v.u + 0x7fffu + ((v.u >> 16) & 1u)) >> 16);
}

__device__ __forceinline__ void store_bf16x4(unsigned short* p, floatx4 v) {
    union { unsigned short u[4]; uint2 q; } pk;
    pk.u[0] = f32_to_bf16_bits(v[0]);
    pk.u[1] = f32_to_bf16_bits(v[1]);
    pk.u[2] = f32_to_bf16_bits(v[2]);
    pk.u[3] = f32_to_bf16_bits(v[3]);
    *(uint2*)p = pk.q;
}

__device__ __forceinline__ floatx4 load_bf16x4(const unsigned short* p) {
    uint2 q = *(const uint2*)p;
    union { unsigned u; float f; } a, b, c, d;
    a.u = q.x << 16; b.u = q.x & 0xffff0000u;
    c.u = q.y << 16; d.u = q.y & 0xffff0000u;
    floatx4 r = {a.f, b.f, c.f, d.f};
    return r;
}

// fast tanh: 1 - 2/(e^{2x}+1); saturates correctly for |x| large
__device__ __forceinline__ float fast_tanh(float x) {
    float e = __expf(2.0f * x);
    return 1.0f - 2.0f / (e + 1.0f);
}

// async 16B global -> LDS DMA. LDS dest = wave-uniform base + lane*16
// (our lds ptrs are tid-linear, so per-wave this holds).
__device__ __forceinline__ void g2l16(const unsigned short* g, char* l) {
    __builtin_amdgcn_global_load_lds(
        (const __attribute__((address_space(1))) void*)g,
        (__attribute__((address_space(3))) void*)l, 16, 0, 0);
}

// C[M,N] tile = A[M,K] @ B[K,N]; A row-major bf16 (lda), Bt=B^T row-major (ldb).
// Tile 64(M) x 128(N), BK=64, **2 waves** (128 thr), each wave owns 64x64
// -> per K32: 8 ds_read_b128 feed 16 MFMA (ratio 2.0 vs 1.33 of the 64x32
// wave shape) — raises the LDS-BW ceiling ~860 -> ~1145 TF.
// 24KB LDS, __launch_bounds__(128,2) -> 4 blocks/CU at 512-block grids.
// Row = 128B = 8 chunks of 16B; chunk ch holds k-chunk ch ^ (row & 7):
// conflict-free DMA writes, <=2-way (free) ds_read_b128.
// MODE 1: Hbf = bf16(tanh(acc + bias[n])), LDS-restaged coalesced store.
// MODE 0: split-K partial -> **bf16** parts (z = K-chunk), LDS-restaged.
//         No fences/atomics (R2 lesson: device fences in-loop thrash L2).
template<int MODE>
__global__ __launch_bounds__(128, 2)
void gemm_bt(const unsigned short* __restrict__ A,
             const unsigned short* __restrict__ Bt,
             const float* __restrict__ bias,
             void* __restrict__ Cout,
             int lda, int ldb, int ldc, int K, long long partStride)
{
    // sA: [64 rows][128B] = 8KB @0; sB: [128 rows][128B] = 16KB @8192.
    __shared__ __align__(16) char smem[24576];
    char* sA = smem;
    char* sB = smem + 8192;

    const int tid  = threadIdx.x;
    const int wave = tid >> 6;
    const int lane = tid & 63;
    const int wn = wave * 64;          // wave col offset in tile
    const int lr = lane & 15;
    const int q  = lane >> 4;

    const int rowBase = blockIdx.y * 64;
    const int colBase = blockIdx.x * 128;
    const long long koff = (long long)blockIdx.z * K;

    // staging: 24KB / (128 thr * 16B) = 12 calls; 4 -> sA, 8 -> sB.
    // call j covers rows j*16..j*16+15 (8 tids per row, 8 chunks).
    const int srow = tid >> 3;            // 0..15 row within a pass
    const int sch  = tid & 7;             // chunk slot
    const int ssc  = sch ^ (srow & 7);    // swizzled k-chunk
    const unsigned short* gA = A + (long long)(rowBase + srow) * lda + koff + ssc * 8;
    const unsigned short* gB = Bt + (long long)(colBase + srow) * ldb + koff + ssc * 8;
    char* lA = sA + tid * 16;             // call j adds j*2048
    char* lB = sB + tid * 16;

    floatx4 acc[4][4];
#pragma unroll
    for (int mi = 0; mi < 4; ++mi)
#pragma unroll
        for (int ni = 0; ni < 4; ++ni) {
            floatx4 z4 = {0.f, 0.f, 0.f, 0.f};
            acc[mi][ni] = z4;
        }

    const int xr = lr & 7;
    int aOff[4], bOff[4];
#pragma unroll
    for (int i = 0; i < 4; ++i) {
        aOff[i] = (i * 16 + lr) * 128;
        bOff[i] = (wn + i * 16 + lr) * 128;
    }

    const long long stepA = 16LL * lda;   // elements per staging row-group
    const long long stepB = 16LL * ldb;

    const int KB = K >> 6;  // BK = 64
    for (int kb = 0; kb < KB; ++kb) {
        if (kb) __syncthreads();
        const int kadv = kb * 64;
#pragma unroll
        for (int j = 0; j < 4; ++j)
            g2l16(gA + j * stepA + kadv, lA + j * 2048);
#pragma unroll
        for (int j = 0; j < 8; ++j)
            g2l16(gB + j * stepB + kadv, lB + j * 2048);
        __syncthreads();

#pragma unroll
        for (int g = 0; g < 2; ++g) {
            const int swz = ((g * 4 + q) ^ xr) * 16;
            short8 af[4], bfr[4];
#pragma unroll
            for (int i = 0; i < 4; ++i) {
                af[i]  = *(const short8*)(sA + aOff[i] + swz);
                bfr[i] = *(const short8*)(sB + bOff[i] + swz);
            }
#pragma unroll
            for (int mi = 0; mi < 4; ++mi)
#pragma unroll
                for (int ni = 0; ni < 4; ++ni)
                    acc[mi][ni] = __builtin_amdgcn_mfma_f32_16x16x32_bf16(
                        af[mi], bfr[ni], acc[mi][ni], 0, 0, 0);
        }
    }

    // ---- epilogue: LDS restage (both modes), bf16 out, coalesced uint4 ----
    __syncthreads();  // done reading sA/sB; reuse smem as sC [64][136] bf16
    unsigned short* sC = (unsigned short*)smem;
    float bias4[4];
    if (MODE == 1) {
#pragma unroll
        for (int ni = 0; ni < 4; ++ni)
            bias4[ni] = bias[colBase + wn + ni * 16 + lr];
    }
#pragma unroll
    for (int mi = 0; mi < 4; ++mi)
#pragma unroll
        for (int ni = 0; ni < 4; ++ni)
#pragma unroll
            for (int r = 0; r < 4; ++r) {
                const int row = mi * 16 + q * 4 + r;
                const int col = wn + ni * 16 + lr;
                const float v = acc[mi][ni][r];
                sC[row * 136 + col] = f32_to_bf16_bits(
                    MODE == 1 ? fast_tanh(v + bias4[ni]) : v);
            }
    __syncthreads();
    unsigned short* C = (unsigned short*)Cout +
                        (MODE == 0 ? (long long)blockIdx.z * partStride : 0LL);
#pragma unroll
    for (int it = 0; it < 8; ++it) {
        const int row = it * 8 + (tid >> 4);
        const int cc  = (tid & 15) * 8;
        *(uint4*)(C + (long long)(rowBase + row) * ldc + colBase + cc) =
            *(const uint4*)(sC + row * 136 + cc);
    }
}

// k = sum_z parts_bf16[z] + b2;  RK4 state update + bf16 next matmul input.
__global__ void combine(const unsigned short* __restrict__ parts,
                        const float* __restrict__ b2,
                        const float* __restrict__ ycur,
                        const float* __restrict__ tspan,
                        int step, int mode,
                        float* __restrict__ kacc,
                        unsigned short* __restrict__ ybf,
                        float* __restrict__ ynext)
{
    const int i = blockIdx.x * blockDim.x + threadIdx.x;  // over BATCH*DIM/4
    const float h = tspan[step + 1] - tspan[step];
    const int NV = BATCH * DIM;
    floatx4 k = load_bf16x4(parts + i * 4)
              + load_bf16x4(parts + i * 4 + NV)
              + load_bf16x4(parts + i * 4 + 2 * NV)
              + load_bf16x4(parts + i * 4 + 3 * NV);
    k = k + *(const floatx4*)(b2 + ((i * 4) & (DIM - 1)));
    floatx4 y = ((const floatx4*)ycur)[i];
    floatx4* ka = (floatx4*)kacc;
    if (mode == 1) {
        ka[i] = k;
        store_bf16x4(ybf + i * 4, y + (0.5f * h) * k);
    } else if (mode == 2) {
        ka[i] = ka[i] + 2.0f * k;
        store_bf16x4(ybf + i * 4, y + (0.5f * h) * k);
    } else if (mode == 3) {
        ka[i] = ka[i] + 2.0f * k;
        store_bf16x4(ybf + i * 4, y + h * k);
    } else {
        floatx4 yn = y + (h * (1.0f / 6.0f)) * (ka[i] + k);
        ((floatx4*)ynext)[i] = yn;
        store_bf16x4(ybf + i * 4, yn);
    }
}

// out[c][r] = bf16(in[r][c]); in is R x C fp32.
__global__ void transpose_cast(const float* __restrict__ in,
                               unsigned short* __restrict__ out, int R, int C)
{
    __shared__ float tile[32][33];
    const int bx = blockIdx.x * 32;
    const int by = blockIdx.y * 32;
    const int tx = threadIdx.x, ty = threadIdx.y;  // (32, 8)
#pragma unroll
    for (int i = 0; i < 4; ++i)
        tile[ty + i * 8][tx] = in[(long long)(by + ty + i * 8) * C + bx + tx];
    __syncthreads();
#pragma unroll
    for (int i = 0; i < 4; ++i)
        out[(long long)(bx + ty + i * 8) * R + by + tx] =
            f32_to_bf16_bits(tile[tx][ty + i * 8]);
}

// d_out[0:16] = t_span; traj[0] = y_init; ybf = bf16(y_init)
__global__ void init_kernel(const float* __restrict__ y0,
                            const float* __restrict__ tspan,
                            float* __restrict__ out,
                            unsigned short* __restrict__ ybf)
{
    const int i = blockIdx.x * blockDim.x + threadIdx.x;
    floatx4 v = ((const floatx4*)y0)[i];
    ((floatx4*)(out + TPTS))[i] = v;
    store_bf16x4(ybf + i * 4, v);
    if (blockIdx.x == 0 && threadIdx.x < TPTS) out[threadIdx.x] = tspan[threadIdx.x];
}

extern "C" void kernel_launch(void* const* d_in, const int* in_sizes, int n_in,
                              void* d_out, int out_size, void* d_ws, size_t ws_size,
                              hipStream_t stream)
{
    (void)in_sizes; (void)n_in; (void)out_size; (void)ws_size;
    const float* y0    = (const float*)d_in[0];
    const float* tspan = (const float*)d_in[1];
    const float* W1    = (const float*)d_in[2];
    const float* b1    = (const float*)d_in[3];
    const float* W2    = (const float*)d_in[4];
    const float* b2    = (const float*)d_in[5];
    float* out = (float*)d_out;

    char* ws = (char*)d_ws;
    unsigned short* W1T = (unsigned short*)(ws);                // [HID][DIM] bf16   8MB
    unsigned short* W2T = (unsigned short*)(ws + (8ll << 20));  // [DIM][HID] bf16   8MB
    unsigned short* Ybf = (unsigned short*)(ws + (16ll << 20)); // [BATCH][DIM] bf16 2MB
    unsigned short* Hbf = (unsigned short*)(ws + (18ll << 20)); // [BATCH][HID] bf16 8MB
    unsigned short* parts = (unsigned short*)(ws + (26ll << 20)); // [4][B][D] bf16  8MB
    float* kacc  = (float*)(ws + (42ll << 20));                 // [BATCH][DIM]      4MB

    dim3 tb(32, 8);
    transpose_cast<<<dim3(HID / 32, DIM / 32), tb, 0, stream>>>(W1, W1T, DIM, HID);
    transpose_cast<<<dim3(DIM / 32, HID / 32), tb, 0, stream>>>(W2, W2T, HID, DIM);
    init_kernel<<<BATCH * DIM / 1024, 256, 0, stream>>>(y0, tspan, out, Ybf);

    float* traj = out + TPTS;
    for (int t = 0; t < TPTS - 1; ++t) {
        const float* ycur = traj + (long long)t * BATCH * DIM;
        float* ynext = traj + (long long)(t + 1) * BATCH * DIM;
        for (int e = 0; e < 4; ++e) {
            // H = tanh(Y @ W1 + b1) -> bf16 [BATCH][HID]; 512 blocks, 4/CU
            gemm_bt<1><<<dim3(HID / 128, BATCH / 64, 1), 128, 0, stream>>>(
                Ybf, W1T, b1, (void*)Hbf, DIM, DIM, HID, DIM, 0LL);
            // parts[z] = H[:,z*1024:+1024] @ W2[z*1024:+1024,:]; 512 blocks
            gemm_bt<0><<<dim3(DIM / 128, BATCH / 64, 4), 128, 0, stream>>>(
                Hbf, W2T, nullptr, (void*)parts, HID, HID, DIM, HID / 4,
                (long long)BATCH * DIM);
            // k_e = sum(parts) + b2 ; RK4 update ; next Ybf
            combine<<<BATCH * DIM / 1024, 256, 0, stream>>>(
                parts, b2, ycur, tspan, t, e + 1, kacc, Ybf, ynext);
        }
    }
}